// Round 2
// baseline (403.793 us; speedup 1.0000x reference)
//
#include <hip/hip_runtime.h>
#include <hip/hip_bf16.h>

#define N_NODES 50000
#define N_EDGES 600000
#define N_GRAPHS 100
#define M_PAD 50176  // 392 * 128
#define TSLICE ((size_t)M_PAD * 32)   // elements per 32-col tile slice

typedef __bf16 bf16_t;
typedef __attribute__((ext_vector_type(8))) __bf16 bf16x8;
typedef __attribute__((ext_vector_type(4))) __bf16 bf16x4;
typedef __attribute__((ext_vector_type(2))) __bf16 bf16x2;
typedef __attribute__((ext_vector_type(4))) float f32x4;

// ---------------- degree ----------------
__global__ void degk(const int* __restrict__ dst, int* __restrict__ deg, int n) {
    int i = blockIdx.x * 256 + threadIdx.x;
    if (i < n) atomicAdd(&deg[dst[i]], 1);
}

// ---------------- scan part 1: per-1024-chunk inclusive scan + norm ----------------
__global__ __launch_bounds__(1024) void scan1(const int* __restrict__ deg,
                                              int* __restrict__ row_off,
                                              int* __restrict__ partial,
                                              float* __restrict__ norm, int n) {
    __shared__ int buf[1024];
    int i = blockIdx.x * 1024 + threadIdx.x;
    int v = (i < n) ? deg[i] : 0;
    buf[threadIdx.x] = v;
    __syncthreads();
    for (int off = 1; off < 1024; off <<= 1) {
        int t = (threadIdx.x >= off) ? buf[threadIdx.x - off] : 0;
        __syncthreads();
        buf[threadIdx.x] += t;
        __syncthreads();
    }
    if (i < n) {
        row_off[i + 1] = buf[threadIdx.x];
        float d = fmaxf((float)v, 1.0f);
        norm[i] = 1.0f / sqrtf(d);
    }
    if (threadIdx.x == 1023) partial[blockIdx.x] = buf[1023];  // chunk total
}

// ---------------- scan part 2 (fused): add prefix of chunk totals ----------------
// Each 256-thread block lies entirely within one 1024-chunk; wave 0 re-reduces
// the <=49 chunk totals (L2-hot) instead of a separate scan kernel.
__global__ __launch_bounds__(256) void scan3(int* __restrict__ row_off,
                                             const int* __restrict__ partial, int n) {
    int i = blockIdx.x * 256 + threadIdx.x;
    int c = (blockIdx.x * 256) >> 10;    // chunk index of this block
    __shared__ int pre;
    if (threadIdx.x < 64) {
        int v = (threadIdx.x < c) ? partial[threadIdx.x] : 0;
        for (int off = 32; off; off >>= 1) v += __shfl_down(v, off, 64);
        if (threadIdx.x == 0) pre = v;
    }
    __syncthreads();
    if (i == 0) row_off[0] = 0;
    if (i < n) row_off[i + 1] += pre;
}

// ---------------- CSR scatter ----------------
__global__ void scatterk(const int* __restrict__ src, const int* __restrict__ dst,
                         const int* __restrict__ row_off, int* __restrict__ cursor,
                         int* __restrict__ csr_src, int n) {
    int e = blockIdx.x * 256 + threadIdx.x;
    if (e >= n) return;
    int d = dst[e];
    int pos = atomicAdd(&cursor[d], 1);
    csr_src[row_off[d] + pos] = src[e];
}

// ---------------- fused prep: prescale (tile-major) + both W permutes ----------------
// blocks [0, npre): xb[tile][node][32] = bf16(x[node][tile*32..])
// blocks [npre, ...): W -> MFMA B-fragment layout (bf16)
#define NPRE (N_NODES * 32 / 256)   // 6250 exactly
__global__ void prep(const float* __restrict__ x, bf16_t* __restrict__ xb,
                     const float* __restrict__ W1, bf16_t* __restrict__ Wp1,
                     const float* __restrict__ W2, bf16_t* __restrict__ Wp2) {
    int b = blockIdx.x;
    if (b < NPRE) {
        int i = b * 256 + threadIdx.x;        // one thread per 4 elements
        int node = i >> 5, c4 = i & 31;       // c4: which float4 of the row
        float4 v = *(const float4*)(x + (size_t)node * 128 + c4 * 4);
        bf16x4 o;
        o[0] = (bf16_t)v.x; o[1] = (bf16_t)v.y; o[2] = (bf16_t)v.z; o[3] = (bf16_t)v.w;
        *(bf16x4*)(xb + (size_t)(c4 >> 3) * TSLICE + (size_t)node * 32 + (c4 & 7) * 4) = o;
    } else {
        int i = (b - NPRE) * 256 + threadIdx.x;
        const float* W; bf16_t* Wp; int N; int idx;
        if (i < 384 * 128)                 { W = W1; Wp = Wp1; N = 128; idx = i; }
        else if (i < 384 * 128 + 384 * 64) { W = W2; Wp = Wp2; N = 64;  idx = i - 384 * 128; }
        else return;
        int k = idx / N, n = idx - k * N;
        int kt = k >> 5, q = (k >> 3) & 3, j = k & 7;
        int nt = n >> 4, ln = n & 15;
        int lane = q * 16 + ln;
        Wp[(((size_t)kt * (N >> 4) + nt) * 64 + lane) * 8 + j] = (bf16_t)W[idx];
    }
}

// ---------------- column-tiled SpMM, tile-major layout ----------------
// out[t][d][:] = norm[d] * sum_{s->d} norm[s] * in[t][s][:]
// Slice per tile = 50176*64B = 3.2MB contiguous & line-aligned -> L2-resident/XCD.
// 3125 blocks/tile keeps phases temporally separated. csr stream nontemporal so
// it doesn't evict the slice; output stores nontemporal (no reuse this phase).
__global__ __launch_bounds__(256) void spmm_t32(const bf16_t* __restrict__ in,
                                                bf16_t* __restrict__ out,
                                                const float* __restrict__ norm,
                                                const int* __restrict__ row_off,
                                                const int* __restrict__ csr_src,
                                                int n, int nodeblocks) {
    int tile = blockIdx.x / nodeblocks;          // 0..3
    int nb   = blockIdx.x - tile * nodeblocks;
    int tid  = threadIdx.x;
    int sub  = tid >> 4;                          // 16 nodes per block
    int l    = tid & 15;                          // 2 cols per lane
    int node = nb * 16 + sub;
    if (node >= n) return;
    int e0 = row_off[node], e1 = row_off[node + 1];
    const bf16_t* base = in + (size_t)tile * TSLICE + l * 2;
    float a0 = 0.f, a1 = 0.f;
    int e = e0;
    for (; e + 8 <= e1; e += 8) {
        int s0 = __builtin_nontemporal_load(csr_src + e + 0);
        int s1 = __builtin_nontemporal_load(csr_src + e + 1);
        int s2 = __builtin_nontemporal_load(csr_src + e + 2);
        int s3 = __builtin_nontemporal_load(csr_src + e + 3);
        int s4 = __builtin_nontemporal_load(csr_src + e + 4);
        int s5 = __builtin_nontemporal_load(csr_src + e + 5);
        int s6 = __builtin_nontemporal_load(csr_src + e + 6);
        int s7 = __builtin_nontemporal_load(csr_src + e + 7);
        float w0 = norm[s0], w1 = norm[s1], w2 = norm[s2], w3 = norm[s3];
        float w4 = norm[s4], w5 = norm[s5], w6 = norm[s6], w7 = norm[s7];
        bf16x2 v0 = *(const bf16x2*)(base + (size_t)s0 * 32);
        bf16x2 v1 = *(const bf16x2*)(base + (size_t)s1 * 32);
        bf16x2 v2 = *(const bf16x2*)(base + (size_t)s2 * 32);
        bf16x2 v3 = *(const bf16x2*)(base + (size_t)s3 * 32);
        bf16x2 v4 = *(const bf16x2*)(base + (size_t)s4 * 32);
        bf16x2 v5 = *(const bf16x2*)(base + (size_t)s5 * 32);
        bf16x2 v6 = *(const bf16x2*)(base + (size_t)s6 * 32);
        bf16x2 v7 = *(const bf16x2*)(base + (size_t)s7 * 32);
        a0 += (w0 * (float)v0[0] + w1 * (float)v1[0]) + (w2 * (float)v2[0] + w3 * (float)v3[0])
            + (w4 * (float)v4[0] + w5 * (float)v5[0]) + (w6 * (float)v6[0] + w7 * (float)v7[0]);
        a1 += (w0 * (float)v0[1] + w1 * (float)v1[1]) + (w2 * (float)v2[1] + w3 * (float)v3[1])
            + (w4 * (float)v4[1] + w5 * (float)v5[1]) + (w6 * (float)v6[1] + w7 * (float)v7[1]);
    }
    if (e + 4 <= e1) {
        int s0 = __builtin_nontemporal_load(csr_src + e + 0);
        int s1 = __builtin_nontemporal_load(csr_src + e + 1);
        int s2 = __builtin_nontemporal_load(csr_src + e + 2);
        int s3 = __builtin_nontemporal_load(csr_src + e + 3);
        float w0 = norm[s0], w1 = norm[s1], w2 = norm[s2], w3 = norm[s3];
        bf16x2 v0 = *(const bf16x2*)(base + (size_t)s0 * 32);
        bf16x2 v1 = *(const bf16x2*)(base + (size_t)s1 * 32);
        bf16x2 v2 = *(const bf16x2*)(base + (size_t)s2 * 32);
        bf16x2 v3 = *(const bf16x2*)(base + (size_t)s3 * 32);
        a0 += (w0 * (float)v0[0] + w1 * (float)v1[0]) + (w2 * (float)v2[0] + w3 * (float)v3[0]);
        a1 += (w0 * (float)v0[1] + w1 * (float)v1[1]) + (w2 * (float)v2[1] + w3 * (float)v3[1]);
        e += 4;
    }
    for (; e < e1; e++) {
        int s = __builtin_nontemporal_load(csr_src + e);
        float ws = norm[s];
        bf16x2 v = *(const bf16x2*)(base + (size_t)s * 32);
        a0 += ws * (float)v[0];
        a1 += ws * (float)v[1];
    }
    float nd = norm[node];
    bf16x2 o;
    o[0] = (bf16_t)(a0 * nd);
    o[1] = (bf16_t)(a1 * nd);
    __builtin_nontemporal_store(o, (bf16x2*)(out + (size_t)tile * TSLICE + (size_t)node * 32 + l * 2));
}

// ---------------- MFMA concat-GEMM (tile-major A): out = relu([f0|f1|f2] @ W + b) ----
template <int NT, bool LAYER1>
__global__ __launch_bounds__(256) void gemm_mfma(const bf16_t* __restrict__ f0,
                                                 const bf16_t* __restrict__ f1,
                                                 const bf16_t* __restrict__ f2,
                                                 const bf16_t* __restrict__ Wp,
                                                 const float* __restrict__ bias,
                                                 bf16_t* __restrict__ out_b,
                                                 float* __restrict__ out_f, int M) {
    int wave = threadIdx.x >> 6;
    int lane = threadIdx.x & 63;
    int q = lane >> 4, ln = lane & 15;
    int row0 = blockIdx.x * 128 + wave * 32;

    f32x4 acc[2][NT] = {};
    const bf16_t* feats[3] = {f0, f1, f2};
    const bf16x8* Wf = (const bf16x8*)Wp;

#pragma unroll
    for (int kc = 0; kc < 12; kc++) {
        // tile-major: feature (kc>>2), col-tile (kc&3), col-in-tile q*8..q*8+7
        const bf16_t* A = feats[kc >> 2] + (size_t)(kc & 3) * TSLICE + q * 8;
        bf16x8 a0 = *(const bf16x8*)(A + (size_t)(row0 + ln) * 32);
        bf16x8 a1 = *(const bf16x8*)(A + (size_t)(row0 + 16 + ln) * 32);
        const bf16x8* Bp = Wf + (size_t)kc * NT * 64 + lane;
#pragma unroll
        for (int nt = 0; nt < NT; nt++) {
            bf16x8 b = Bp[nt * 64];
            acc[0][nt] = __builtin_amdgcn_mfma_f32_16x16x32_bf16(a0, b, acc[0][nt], 0, 0, 0);
            acc[1][nt] = __builtin_amdgcn_mfma_f32_16x16x32_bf16(a1, b, acc[1][nt], 0, 0, 0);
        }
    }

    float bv[NT];
#pragma unroll
    for (int nt = 0; nt < NT; nt++) bv[nt] = bias[nt * 16 + ln];

#pragma unroll
    for (int mt = 0; mt < 2; mt++) {
#pragma unroll
        for (int r = 0; r < 4; r++) {
            int row = row0 + mt * 16 + q * 4 + r;
            if (row >= M) continue;
#pragma unroll
            for (int nt = 0; nt < NT; nt++) {
                float val = fmaxf(acc[mt][nt][r] + bv[nt], 0.f);
                if (LAYER1) {
                    // tile-major write: col = nt*16+ln -> tile nt>>1, in-tile (nt&1)*16+ln
                    out_b[(size_t)(nt >> 1) * TSLICE + (size_t)row * 32 + (nt & 1) * 16 + ln] = (bf16_t)val;
                } else {
                    out_f[(size_t)row * 64 + nt * 16 + ln] = val;
                }
            }
        }
    }
}

// ---------------- parallel per-graph max pool ----------------
__global__ __launch_bounds__(256) void maxpool2(const float* __restrict__ hF,
                                                const int* __restrict__ gid,
                                                unsigned int* __restrict__ out, int n) {
    int wave = threadIdx.x >> 6;
    int lane = threadIdx.x & 63;
    int n0 = blockIdx.x * 256 + wave * 64;
    if (n0 >= n) return;
    int n1 = min(n0 + 64, n);
    int cur = gid[n0];
    float m = 0.f;
    int i = n0;
    for (; i + 4 <= n1; i += 4) {
        int g0 = gid[i + 0], g1 = gid[i + 1], g2 = gid[i + 2], g3 = gid[i + 3];
        float v0 = hF[(size_t)(i + 0) * 64 + lane];
        float v1 = hF[(size_t)(i + 1) * 64 + lane];
        float v2 = hF[(size_t)(i + 2) * 64 + lane];
        float v3 = hF[(size_t)(i + 3) * 64 + lane];
        if (g0 != cur) { atomicMax(&out[cur * 64 + lane], __float_as_uint(m)); cur = g0; m = v0; } else m = fmaxf(m, v0);
        if (g1 != cur) { atomicMax(&out[cur * 64 + lane], __float_as_uint(m)); cur = g1; m = v1; } else m = fmaxf(m, v1);
        if (g2 != cur) { atomicMax(&out[cur * 64 + lane], __float_as_uint(m)); cur = g2; m = v2; } else m = fmaxf(m, v2);
        if (g3 != cur) { atomicMax(&out[cur * 64 + lane], __float_as_uint(m)); cur = g3; m = v3; } else m = fmaxf(m, v3);
    }
    for (; i < n1; i++) {
        int g = gid[i];
        float v = hF[(size_t)i * 64 + lane];
        if (g != cur) { atomicMax(&out[cur * 64 + lane], __float_as_uint(m)); cur = g; m = v; }
        else m = fmaxf(m, v);
    }
    atomicMax(&out[cur * 64 + lane], __float_as_uint(m));
}

extern "C" void kernel_launch(void* const* d_in, const int* in_sizes, int n_in,
                              void* d_out, int out_size, void* d_ws, size_t ws_size,
                              hipStream_t stream) {
    const float* x  = (const float*)d_in[0];
    const float* W1 = (const float*)d_in[1];
    const float* b1 = (const float*)d_in[2];
    const float* W2 = (const float*)d_in[3];
    const float* b2 = (const float*)d_in[4];
    const int* src  = (const int*)d_in[5];
    const int* dst  = (const int*)d_in[6];
    const int* gid  = (const int*)d_in[7];
    float* out = (float*)d_out;

    char* ws = (char*)d_ws;
    size_t off = 0;
    auto take = [&](size_t bytes) {
        void* p = ws + off;
        off = (off + bytes + 255) & ~(size_t)255;
        return p;
    };
    int* deg     = (int*)take((size_t)N_NODES * 4);
    int* cursor  = (int*)take((size_t)N_NODES * 4);
    size_t zero_bytes = off;
    float* norm  = (float*)take((size_t)N_NODES * 4);
    int* row_off = (int*)take((size_t)(N_NODES + 1) * 4);
    int* partial = (int*)take(64 * 4);
    int* csr_src = (int*)take((size_t)N_EDGES * 4);
    bf16_t* Wp1  = (bf16_t*)take((size_t)384 * 128 * 2);
    bf16_t* Wp2  = (bf16_t*)take((size_t)384 * 64 * 2);
    bf16_t* B0 = (bf16_t*)take((size_t)M_PAD * 128 * 2);  // xb (tile-major) -> hF (fp32 64c)
    bf16_t* B1 = (bf16_t*)take((size_t)M_PAD * 128 * 2);  // c1 -> d1 (tile-major)
    bf16_t* B2 = (bf16_t*)take((size_t)M_PAD * 128 * 2);  // c2 -> d2 (tile-major)
    bf16_t* B3 = (bf16_t*)take((size_t)M_PAD * 128 * 2);  // hL1 (tile-major)
    (void)ws_size; (void)in_sizes; (void)n_in; (void)out_size;

    hipMemsetAsync(d_ws, 0, zero_bytes, stream);
    hipMemsetAsync(d_out, 0, (size_t)N_GRAPHS * 64 * 4, stream);

    prep<<<NPRE + (384 * 192 + 255) / 256, 256, 0, stream>>>(x, B0, W1, Wp1, W2, Wp2);

    degk<<<(N_EDGES + 255) / 256, 256, 0, stream>>>(dst, deg, N_EDGES);
    int nchunks = (N_NODES + 1023) / 1024;
    scan1<<<nchunks, 1024, 0, stream>>>(deg, row_off, partial, norm, N_NODES);
    scan3<<<(N_NODES + 255) / 256, 256, 0, stream>>>(row_off, partial, N_NODES);
    scatterk<<<(N_EDGES + 255) / 256, 256, 0, stream>>>(src, dst, row_off, cursor, csr_src, N_EDGES);

    int nodeblocks = (N_NODES + 15) / 16;      // 3125
    int spmm_grid  = 4 * nodeblocks;           // tile-major phases
    int gemm_grid  = M_PAD / 128;              // 392

    // layer 1 hops
    spmm_t32<<<spmm_grid, 256, 0, stream>>>(B0, B1, norm, row_off, csr_src, N_NODES, nodeblocks);
    spmm_t32<<<spmm_grid, 256, 0, stream>>>(B1, B2, norm, row_off, csr_src, N_NODES, nodeblocks);
    // layer 1 GEMM -> hL1 (B3, tile-major)
    gemm_mfma<8, true><<<gemm_grid, 256, 0, stream>>>(B0, B1, B2, Wp1, b1, B3, nullptr, N_NODES);
    // layer 2 hops
    spmm_t32<<<spmm_grid, 256, 0, stream>>>(B3, B1, norm, row_off, csr_src, N_NODES, nodeblocks);
    spmm_t32<<<spmm_grid, 256, 0, stream>>>(B1, B2, norm, row_off, csr_src, N_NODES, nodeblocks);
    // layer 2 GEMM -> hF (B0 as fp32, 64 cols, node-major)
    gemm_mfma<4, false><<<gemm_grid, 256, 0, stream>>>(B3, B1, B2, Wp2, b2, nullptr, (float*)B0, N_NODES);
    // readout
    maxpool2<<<(N_NODES + 255) / 256, 256, 0, stream>>>((const float*)B0, gid, (unsigned int*)out, N_NODES);
}

// Round 3
// 310.174 us; speedup vs baseline: 1.3018x; 1.3018x over previous
//
#include <hip/hip_runtime.h>
#include <hip/hip_bf16.h>

#define N_NODES 50000
#define N_EDGES 600000
#define N_GRAPHS 100
#define M_PAD 50176  // 392 * 128

typedef __bf16 bf16_t;
typedef __attribute__((ext_vector_type(8))) __bf16 bf16x8;
typedef __attribute__((ext_vector_type(4))) __bf16 bf16x4;
typedef __attribute__((ext_vector_type(2))) __bf16 bf16x2;
typedef __attribute__((ext_vector_type(4))) float f32x4;

// ---------------- degree ----------------
__global__ void degk(const int* __restrict__ dst, int* __restrict__ deg, int n) {
    int i = blockIdx.x * 256 + threadIdx.x;
    if (i < n) atomicAdd(&deg[dst[i]], 1);
}

// ---------------- scan part 1: per-1024-chunk inclusive scan + norm ----------------
__global__ __launch_bounds__(1024) void scan1(const int* __restrict__ deg,
                                              int* __restrict__ row_off,
                                              int* __restrict__ partial,
                                              float* __restrict__ norm, int n) {
    __shared__ int buf[1024];
    int i = blockIdx.x * 1024 + threadIdx.x;
    int v = (i < n) ? deg[i] : 0;
    buf[threadIdx.x] = v;
    __syncthreads();
    for (int off = 1; off < 1024; off <<= 1) {
        int t = (threadIdx.x >= off) ? buf[threadIdx.x - off] : 0;
        __syncthreads();
        buf[threadIdx.x] += t;
        __syncthreads();
    }
    if (i < n) {
        row_off[i + 1] = buf[threadIdx.x];
        float d = fmaxf((float)v, 1.0f);
        norm[i] = 1.0f / sqrtf(d);
    }
    if (threadIdx.x == 1023) partial[blockIdx.x] = buf[1023];  // chunk total
}

// ---------------- scan part 2 (fused): add prefix of chunk totals ----------------
__global__ __launch_bounds__(256) void scan3(int* __restrict__ row_off,
                                             const int* __restrict__ partial, int n) {
    int i = blockIdx.x * 256 + threadIdx.x;
    int c = (blockIdx.x * 256) >> 10;    // chunk index of this block
    __shared__ int pre;
    if (threadIdx.x < 64) {
        int v = (threadIdx.x < c) ? partial[threadIdx.x] : 0;
        for (int off = 32; off; off >>= 1) v += __shfl_down(v, off, 64);
        if (threadIdx.x == 0) pre = v;
    }
    __syncthreads();
    if (i == 0) row_off[0] = 0;
    if (i < n) row_off[i + 1] += pre;
}

// ---------------- fused mid kernel: prescale | CSR scatter | W permute ----------------
// All three depend only on {norm, row_off} (ready after scan3) and are independent.
#define NPRE 6250                       // N_NODES*32/256
#define NSC  ((N_EDGES + 255) / 256)    // 2344
#define NPW  ((384 * 192 + 255) / 256)  // 288
__global__ __launch_bounds__(256) void midk(const float* __restrict__ x,
                                            const float* __restrict__ norm,
                                            bf16_t* __restrict__ xb, bf16_t* __restrict__ xs,
                                            const int* __restrict__ src, const int* __restrict__ dst,
                                            const int* __restrict__ row_off, int* __restrict__ cursor,
                                            int* __restrict__ csr_src,
                                            const float* __restrict__ W1, bf16_t* __restrict__ Wp1,
                                            const float* __restrict__ W2, bf16_t* __restrict__ Wp2) {
    int b = blockIdx.x;
    if (b < NPRE) {
        // prescale: one thread per float4; xb = bf16(x), xs = bf16(x*norm)
        int i = b * 256 + threadIdx.x;
        int node = i >> 5, c4 = i & 31;
        float4 v = *(const float4*)(x + (size_t)node * 128 + c4 * 4);
        float nd = norm[node];
        bf16x4 ob, os;
        ob[0] = (bf16_t)v.x; ob[1] = (bf16_t)v.y; ob[2] = (bf16_t)v.z; ob[3] = (bf16_t)v.w;
        os[0] = (bf16_t)(v.x * nd); os[1] = (bf16_t)(v.y * nd);
        os[2] = (bf16_t)(v.z * nd); os[3] = (bf16_t)(v.w * nd);
        *(bf16x4*)(xb + (size_t)node * 128 + c4 * 4) = ob;
        *(bf16x4*)(xs + (size_t)node * 128 + c4 * 4) = os;
    } else if (b < NPRE + NSC) {
        int e = (b - NPRE) * 256 + threadIdx.x;
        if (e >= N_EDGES) return;
        int d = dst[e];
        int pos = atomicAdd(&cursor[d], 1);
        csr_src[row_off[d] + pos] = src[e];
    } else {
        int i = (b - NPRE - NSC) * 256 + threadIdx.x;
        const float* W; bf16_t* Wp; int N; int idx;
        if (i < 384 * 128)                 { W = W1; Wp = Wp1; N = 128; idx = i; }
        else if (i < 384 * 128 + 384 * 64) { W = W2; Wp = Wp2; N = 64;  idx = i - 384 * 128; }
        else return;
        int k = idx / N, n = idx - k * N;
        int kt = k >> 5, q = (k >> 3) & 3, j = k & 7;
        int nt = n >> 4, ln = n & 15;
        int lane = q * 16 + ln;
        Wp[(((size_t)kt * (N >> 4) + nt) * 64 + lane) * 8 + j] = (bf16_t)W[idx];
    }
}

// ---------------- SpMM: 16 lanes per dst node, full 256B rows, unroll-8 ----------------
// in is PRE-SCALED by source norm (xs layout) -> loop body is idx -> gather -> fma only.
// One wave instruction gathers 4 full rows (1KB). out_c = nd*sum, out_s = nd^2*sum.
template <bool SCALED>
__global__ __launch_bounds__(256) void spmm_bf16(const bf16_t* __restrict__ in,
                                                 bf16_t* __restrict__ out_c,
                                                 bf16_t* __restrict__ out_s,
                                                 const float* __restrict__ norm,
                                                 const int* __restrict__ row_off,
                                                 const int* __restrict__ csr_src, int n) {
    int tid = threadIdx.x;
    int sub = tid >> 4;   // 16 subgroups per block
    int l   = tid & 15;   // lane within subgroup: feats [l*8, l*8+8)
    int node = blockIdx.x * 16 + sub;
    if (node >= n) return;
    int e0 = row_off[node], e1 = row_off[node + 1];
    const bf16_t* col = in + l * 8;
    float acc[8] = {};
    int e = e0;
    for (; e + 8 <= e1; e += 8) {
        int s0 = csr_src[e + 0];
        int s1 = csr_src[e + 1];
        int s2 = csr_src[e + 2];
        int s3 = csr_src[e + 3];
        int s4 = csr_src[e + 4];
        int s5 = csr_src[e + 5];
        int s6 = csr_src[e + 6];
        int s7 = csr_src[e + 7];
        bf16x8 v0 = *(const bf16x8*)(col + (size_t)s0 * 128);
        bf16x8 v1 = *(const bf16x8*)(col + (size_t)s1 * 128);
        bf16x8 v2 = *(const bf16x8*)(col + (size_t)s2 * 128);
        bf16x8 v3 = *(const bf16x8*)(col + (size_t)s3 * 128);
        bf16x8 v4 = *(const bf16x8*)(col + (size_t)s4 * 128);
        bf16x8 v5 = *(const bf16x8*)(col + (size_t)s5 * 128);
        bf16x8 v6 = *(const bf16x8*)(col + (size_t)s6 * 128);
        bf16x8 v7 = *(const bf16x8*)(col + (size_t)s7 * 128);
#pragma unroll
        for (int j = 0; j < 8; j++)
            acc[j] += (((float)v0[j] + (float)v1[j]) + ((float)v2[j] + (float)v3[j]))
                    + (((float)v4[j] + (float)v5[j]) + ((float)v6[j] + (float)v7[j]));
    }
    if (e + 4 <= e1) {
        int s0 = csr_src[e + 0];
        int s1 = csr_src[e + 1];
        int s2 = csr_src[e + 2];
        int s3 = csr_src[e + 3];
        bf16x8 v0 = *(const bf16x8*)(col + (size_t)s0 * 128);
        bf16x8 v1 = *(const bf16x8*)(col + (size_t)s1 * 128);
        bf16x8 v2 = *(const bf16x8*)(col + (size_t)s2 * 128);
        bf16x8 v3 = *(const bf16x8*)(col + (size_t)s3 * 128);
#pragma unroll
        for (int j = 0; j < 8; j++)
            acc[j] += ((float)v0[j] + (float)v1[j]) + ((float)v2[j] + (float)v3[j]);
        e += 4;
    }
    for (; e < e1; e++) {
        int s = csr_src[e];
        bf16x8 v = *(const bf16x8*)(col + (size_t)s * 128);
#pragma unroll
        for (int j = 0; j < 8; j++) acc[j] += (float)v[j];
    }
    float nd = norm[node];
    bf16x8 oc, os;
#pragma unroll
    for (int j = 0; j < 8; j++) {
        float c = acc[j] * nd;
        oc[j] = (bf16_t)c;
        os[j] = (bf16_t)(c * nd);
    }
    *(bf16x8*)(out_c + (size_t)node * 128 + l * 8) = oc;
    if (SCALED) *(bf16x8*)(out_s + (size_t)node * 128 + l * 8) = os;
}

// ---------------- MFMA concat-GEMM: out = relu([f0|f1|f2] @ W + b) ----------------
template <int NT, bool LAYER1>
__global__ __launch_bounds__(256) void gemm_mfma(const bf16_t* __restrict__ f0,
                                                 const bf16_t* __restrict__ f1,
                                                 const bf16_t* __restrict__ f2,
                                                 const bf16_t* __restrict__ Wp,
                                                 const float* __restrict__ bias,
                                                 const float* __restrict__ norm,
                                                 bf16_t* __restrict__ out_b,
                                                 bf16_t* __restrict__ out_s,
                                                 float* __restrict__ out_f, int M) {
    int wave = threadIdx.x >> 6;
    int lane = threadIdx.x & 63;
    int q = lane >> 4, ln = lane & 15;
    int row0 = blockIdx.x * 128 + wave * 32;

    f32x4 acc[2][NT] = {};
    const bf16_t* feats[3] = {f0, f1, f2};
    const bf16x8* Wf = (const bf16x8*)Wp;

#pragma unroll
    for (int kc = 0; kc < 12; kc++) {
        const bf16_t* A = feats[kc >> 2] + (size_t)(kc & 3) * 32 + q * 8;
        bf16x8 a0 = *(const bf16x8*)(A + (size_t)(row0 + ln) * 128);
        bf16x8 a1 = *(const bf16x8*)(A + (size_t)(row0 + 16 + ln) * 128);
        const bf16x8* Bp = Wf + (size_t)kc * NT * 64 + lane;
#pragma unroll
        for (int nt = 0; nt < NT; nt++) {
            bf16x8 b = Bp[nt * 64];
            acc[0][nt] = __builtin_amdgcn_mfma_f32_16x16x32_bf16(a0, b, acc[0][nt], 0, 0, 0);
            acc[1][nt] = __builtin_amdgcn_mfma_f32_16x16x32_bf16(a1, b, acc[1][nt], 0, 0, 0);
        }
    }

    float bv[NT];
#pragma unroll
    for (int nt = 0; nt < NT; nt++) bv[nt] = bias[nt * 16 + ln];

#pragma unroll
    for (int mt = 0; mt < 2; mt++) {
#pragma unroll
        for (int r = 0; r < 4; r++) {
            int row = row0 + mt * 16 + q * 4 + r;
            if (row >= M) continue;
            float nd = LAYER1 ? norm[row] : 0.f;
#pragma unroll
            for (int nt = 0; nt < NT; nt++) {
                int col = nt * 16 + ln;
                float val = fmaxf(acc[mt][nt][r] + bv[nt], 0.f);
                if (LAYER1) {
                    out_b[(size_t)row * 128 + col] = (bf16_t)val;
                    out_s[(size_t)row * 128 + col] = (bf16_t)(val * nd);
                } else {
                    out_f[(size_t)row * 64 + col] = val;
                }
            }
        }
    }
}

// ---------------- parallel per-graph max pool ----------------
__global__ __launch_bounds__(256) void maxpool2(const float* __restrict__ hF,
                                                const int* __restrict__ gid,
                                                unsigned int* __restrict__ out, int n) {
    int wave = threadIdx.x >> 6;
    int lane = threadIdx.x & 63;
    int n0 = blockIdx.x * 256 + wave * 64;
    if (n0 >= n) return;
    int n1 = min(n0 + 64, n);
    int cur = gid[n0];
    float m = 0.f;
    int i = n0;
    for (; i + 4 <= n1; i += 4) {
        int g0 = gid[i + 0], g1 = gid[i + 1], g2 = gid[i + 2], g3 = gid[i + 3];
        float v0 = hF[(size_t)(i + 0) * 64 + lane];
        float v1 = hF[(size_t)(i + 1) * 64 + lane];
        float v2 = hF[(size_t)(i + 2) * 64 + lane];
        float v3 = hF[(size_t)(i + 3) * 64 + lane];
        if (g0 != cur) { atomicMax(&out[cur * 64 + lane], __float_as_uint(m)); cur = g0; m = v0; } else m = fmaxf(m, v0);
        if (g1 != cur) { atomicMax(&out[cur * 64 + lane], __float_as_uint(m)); cur = g1; m = v1; } else m = fmaxf(m, v1);
        if (g2 != cur) { atomicMax(&out[cur * 64 + lane], __float_as_uint(m)); cur = g2; m = v2; } else m = fmaxf(m, v2);
        if (g3 != cur) { atomicMax(&out[cur * 64 + lane], __float_as_uint(m)); cur = g3; m = v3; } else m = fmaxf(m, v3);
    }
    for (; i < n1; i++) {
        int g = gid[i];
        float v = hF[(size_t)i * 64 + lane];
        if (g != cur) { atomicMax(&out[cur * 64 + lane], __float_as_uint(m)); cur = g; m = v; }
        else m = fmaxf(m, v);
    }
    atomicMax(&out[cur * 64 + lane], __float_as_uint(m));
}

extern "C" void kernel_launch(void* const* d_in, const int* in_sizes, int n_in,
                              void* d_out, int out_size, void* d_ws, size_t ws_size,
                              hipStream_t stream) {
    const float* x  = (const float*)d_in[0];
    const float* W1 = (const float*)d_in[1];
    const float* b1 = (const float*)d_in[2];
    const float* W2 = (const float*)d_in[3];
    const float* b2 = (const float*)d_in[4];
    const int* src  = (const int*)d_in[5];
    const int* dst  = (const int*)d_in[6];
    const int* gid  = (const int*)d_in[7];
    float* out = (float*)d_out;

    char* ws = (char*)d_ws;
    size_t off = 0;
    auto take = [&](size_t bytes) {
        void* p = ws + off;
        off = (off + bytes + 255) & ~(size_t)255;
        return p;
    };
    int* deg     = (int*)take((size_t)N_NODES * 4);
    int* cursor  = (int*)take((size_t)N_NODES * 4);
    size_t zero_bytes = off;
    float* norm  = (float*)take((size_t)N_NODES * 4);
    int* row_off = (int*)take((size_t)(N_NODES + 1) * 4);
    int* partial = (int*)take(64 * 4);
    int* csr_src = (int*)take((size_t)N_EDGES * 4);
    bf16_t* Wp1  = (bf16_t*)take((size_t)384 * 128 * 2);
    bf16_t* Wp2  = (bf16_t*)take((size_t)384 * 64 * 2);
    bf16_t* B0 = (bf16_t*)take((size_t)M_PAD * 128 * 2);  // xb   -> hF (fp32 64c)
    bf16_t* B1 = (bf16_t*)take((size_t)M_PAD * 128 * 2);  // xs   -> hL1s
    bf16_t* B2 = (bf16_t*)take((size_t)M_PAD * 128 * 2);  // c1   -> d1
    bf16_t* B3 = (bf16_t*)take((size_t)M_PAD * 128 * 2);  // c2   -> d2
    bf16_t* B4 = (bf16_t*)take((size_t)M_PAD * 128 * 2);  // c1s  -> d1s
    bf16_t* B5 = (bf16_t*)take((size_t)M_PAD * 128 * 2);  // hL1
    (void)ws_size; (void)in_sizes; (void)n_in; (void)out_size;

    hipMemsetAsync(d_ws, 0, zero_bytes, stream);
    hipMemsetAsync(d_out, 0, (size_t)N_GRAPHS * 64 * 4, stream);

    degk<<<(N_EDGES + 255) / 256, 256, 0, stream>>>(dst, deg, N_EDGES);
    int nchunks = (N_NODES + 1023) / 1024;
    scan1<<<nchunks, 1024, 0, stream>>>(deg, row_off, partial, norm, N_NODES);
    scan3<<<(N_NODES + 255) / 256, 256, 0, stream>>>(row_off, partial, N_NODES);
    midk<<<NPRE + NSC + NPW, 256, 0, stream>>>(x, norm, B0, B1, src, dst, row_off, cursor,
                                               csr_src, W1, Wp1, W2, Wp2);

    int spmm_grid = (N_NODES + 15) / 16;  // 3125
    int gemm_grid = M_PAD / 128;          // 392

    // layer 1 hops
    spmm_bf16<true><<<spmm_grid, 256, 0, stream>>>(B1, B2, B4, norm, row_off, csr_src, N_NODES);
    spmm_bf16<false><<<spmm_grid, 256, 0, stream>>>(B4, B3, nullptr, norm, row_off, csr_src, N_NODES);
    // layer 1 GEMM -> hL1 (B5) + hL1s (B1)
    gemm_mfma<8, true><<<gemm_grid, 256, 0, stream>>>(B0, B2, B3, Wp1, b1, norm, B5, B1, nullptr, N_NODES);
    // layer 2 hops
    spmm_bf16<true><<<spmm_grid, 256, 0, stream>>>(B1, B2, B4, norm, row_off, csr_src, N_NODES);
    spmm_bf16<false><<<spmm_grid, 256, 0, stream>>>(B4, B3, nullptr, norm, row_off, csr_src, N_NODES);
    // layer 2 GEMM -> hF (B0 as fp32, 64 cols)
    gemm_mfma<4, false><<<gemm_grid, 256, 0, stream>>>(B5, B2, B3, Wp2, b2, nullptr, nullptr, nullptr, (float*)B0, N_NODES);
    // readout
    maxpool2<<<(N_NODES + 255) / 256, 256, 0, stream>>>((const float*)B0, gid, (unsigned int*)out, N_NODES);
}

// Round 4
// 281.837 us; speedup vs baseline: 1.4327x; 1.1005x over previous
//
#include <hip/hip_runtime.h>
#include <hip/hip_bf16.h>

#define N_NODES 50000
#define N_EDGES 600000
#define N_GRAPHS 100
#define M_PAD 50176  // 392 * 128
#define TSLICE ((size_t)M_PAD * 32)   // elements per 32-col tile slice

typedef __bf16 bf16_t;
typedef __attribute__((ext_vector_type(8))) __bf16 bf16x8;
typedef __attribute__((ext_vector_type(4))) __bf16 bf16x4;
typedef __attribute__((ext_vector_type(2))) __bf16 bf16x2;
typedef __attribute__((ext_vector_type(4))) float f32x4;

// ---------------- degree + per-edge rank (atomicAdd return value) ----------------
__global__ void degk(const int* __restrict__ dst, int* __restrict__ deg,
                     int* __restrict__ rank, int n) {
    int i = blockIdx.x * 256 + threadIdx.x;
    if (i < n) rank[i] = atomicAdd(&deg[dst[i]], 1);
}

// ---------------- scan part 1: per-1024-chunk inclusive scan + norm ----------------
__global__ __launch_bounds__(1024) void scan1(const int* __restrict__ deg,
                                              int* __restrict__ row_off,
                                              int* __restrict__ partial,
                                              float* __restrict__ norm, int n) {
    __shared__ int buf[1024];
    int i = blockIdx.x * 1024 + threadIdx.x;
    int v = (i < n) ? deg[i] : 0;
    buf[threadIdx.x] = v;
    __syncthreads();
    for (int off = 1; off < 1024; off <<= 1) {
        int t = (threadIdx.x >= off) ? buf[threadIdx.x - off] : 0;
        __syncthreads();
        buf[threadIdx.x] += t;
        __syncthreads();
    }
    if (i < n) {
        row_off[i + 1] = buf[threadIdx.x];
        float d = fmaxf((float)v, 1.0f);
        norm[i] = 1.0f / sqrtf(d);
    }
    if (threadIdx.x == 1023) partial[blockIdx.x] = buf[1023];  // chunk total
}

// ---------------- scan part 2 (fused): add prefix of chunk totals ----------------
__global__ __launch_bounds__(256) void scan3(int* __restrict__ row_off,
                                             const int* __restrict__ partial, int n) {
    int i = blockIdx.x * 256 + threadIdx.x;
    int c = (blockIdx.x * 256) >> 10;    // chunk index of this block
    __shared__ int pre;
    if (threadIdx.x < 64) {
        int v = (threadIdx.x < c) ? partial[threadIdx.x] : 0;
        for (int off = 32; off; off >>= 1) v += __shfl_down(v, off, 64);
        if (threadIdx.x == 0) pre = v;
    }
    __syncthreads();
    if (i == 0) row_off[0] = 0;
    if (i < n) row_off[i + 1] += pre;
}

// ---------------- fused mid kernel: prescale(tile-major) | CSR scatter | W permute ---
// All depend only on {norm, row_off, rank} (ready after scan3/degk) and are independent.
#define NPRE 6250                       // N_NODES*32/256
#define NSC  ((N_EDGES + 255) / 256)    // 2344
#define NPW  ((384 * 192 + 255) / 256)  // 288
__global__ __launch_bounds__(256) void midk(const float* __restrict__ x,
                                            const float* __restrict__ norm,
                                            bf16_t* __restrict__ xb, bf16_t* __restrict__ xs,
                                            const int* __restrict__ src, const int* __restrict__ dst,
                                            const int* __restrict__ row_off,
                                            const int* __restrict__ rank,
                                            int* __restrict__ csr_src,
                                            const float* __restrict__ W1, bf16_t* __restrict__ Wp1,
                                            const float* __restrict__ W2, bf16_t* __restrict__ Wp2) {
    int b = blockIdx.x;
    if (b < NPRE) {
        // prescale: one thread per float4; tile-major xb = bf16(x), xs = bf16(x*norm)
        int i = b * 256 + threadIdx.x;
        int node = i >> 5, c4 = i & 31;          // c4: which float4 of the 128-col row
        float4 v = *(const float4*)(x + (size_t)node * 128 + c4 * 4);
        float nd = norm[node];
        bf16x4 ob, os;
        ob[0] = (bf16_t)v.x; ob[1] = (bf16_t)v.y; ob[2] = (bf16_t)v.z; ob[3] = (bf16_t)v.w;
        os[0] = (bf16_t)(v.x * nd); os[1] = (bf16_t)(v.y * nd);
        os[2] = (bf16_t)(v.z * nd); os[3] = (bf16_t)(v.w * nd);
        size_t t = (size_t)(c4 >> 3) * TSLICE + (size_t)node * 32 + (c4 & 7) * 4;
        *(bf16x4*)(xb + t) = ob;
        *(bf16x4*)(xs + t) = os;
    } else if (b < NPRE + NSC) {
        // CSR scatter: atomic-free (rank precomputed in degk)
        int e = (b - NPRE) * 256 + threadIdx.x;
        if (e >= N_EDGES) return;
        int d = dst[e];
        csr_src[row_off[d] + rank[e]] = src[e];
    } else {
        int i = (b - NPRE - NSC) * 256 + threadIdx.x;
        const float* W; bf16_t* Wp; int N; int idx;
        if (i < 384 * 128)                 { W = W1; Wp = Wp1; N = 128; idx = i; }
        else if (i < 384 * 128 + 384 * 64) { W = W2; Wp = Wp2; N = 64;  idx = i - 384 * 128; }
        else return;
        int k = idx / N, n = idx - k * N;
        int kt = k >> 5, q = (k >> 3) & 3, j = k & 7;
        int nt = n >> 4, ln = n & 15;
        int lane = q * 16 + ln;
        Wp[(((size_t)kt * (N >> 4) + nt) * 64 + lane) * 8 + j] = (bf16_t)W[idx];
    }
}

// ---------------- XCD-spatial tiled SpMM ----------------
// tile = (bid&7)>>1: with round-robin block->XCD dispatch each XCD's L2 holds ONE
// 3.2MB 32-col slice (L2-resident). 4 lanes/node x 16B gathers (64B contiguous per
// node -> same VMEM efficiency as full-row). Input is pre-scaled by source norm, so
// loop = idx -> gather -> add only. out_c = nd*sum, out_s = nd^2*sum (tile-major).
template <bool SCALED>
__global__ __launch_bounds__(256) void spmm_xcd(const bf16_t* __restrict__ in,
                                                bf16_t* __restrict__ out_c,
                                                bf16_t* __restrict__ out_s,
                                                const float* __restrict__ norm,
                                                const int* __restrict__ row_off,
                                                const int* __restrict__ csr_src, int n) {
    int bid  = blockIdx.x;
    int xcd  = bid & 7;
    int tile = xcd >> 1;                 // 2 XCDs per tile
    int sub  = bid >> 3;                 // 0..390
    int grp  = threadIdx.x >> 2;         // 64 nodes per block
    int l    = threadIdx.x & 3;          // cols [l*8, l*8+8) of this tile
    int node = (sub * 2 + (xcd & 1)) * 64 + grp;
    if (node >= n) return;
    int e0 = row_off[node], e1 = row_off[node + 1];
    const bf16_t* base = in + (size_t)tile * TSLICE + l * 8;
    float acc[8] = {};
    int e = e0;
    for (; e + 8 <= e1; e += 8) {
        int s0 = csr_src[e + 0];
        int s1 = csr_src[e + 1];
        int s2 = csr_src[e + 2];
        int s3 = csr_src[e + 3];
        int s4 = csr_src[e + 4];
        int s5 = csr_src[e + 5];
        int s6 = csr_src[e + 6];
        int s7 = csr_src[e + 7];
        bf16x8 v0 = *(const bf16x8*)(base + (size_t)s0 * 32);
        bf16x8 v1 = *(const bf16x8*)(base + (size_t)s1 * 32);
        bf16x8 v2 = *(const bf16x8*)(base + (size_t)s2 * 32);
        bf16x8 v3 = *(const bf16x8*)(base + (size_t)s3 * 32);
        bf16x8 v4 = *(const bf16x8*)(base + (size_t)s4 * 32);
        bf16x8 v5 = *(const bf16x8*)(base + (size_t)s5 * 32);
        bf16x8 v6 = *(const bf16x8*)(base + (size_t)s6 * 32);
        bf16x8 v7 = *(const bf16x8*)(base + (size_t)s7 * 32);
#pragma unroll
        for (int j = 0; j < 8; j++)
            acc[j] += (((float)v0[j] + (float)v1[j]) + ((float)v2[j] + (float)v3[j]))
                    + (((float)v4[j] + (float)v5[j]) + ((float)v6[j] + (float)v7[j]));
    }
    if (e + 4 <= e1) {
        int s0 = csr_src[e + 0];
        int s1 = csr_src[e + 1];
        int s2 = csr_src[e + 2];
        int s3 = csr_src[e + 3];
        bf16x8 v0 = *(const bf16x8*)(base + (size_t)s0 * 32);
        bf16x8 v1 = *(const bf16x8*)(base + (size_t)s1 * 32);
        bf16x8 v2 = *(const bf16x8*)(base + (size_t)s2 * 32);
        bf16x8 v3 = *(const bf16x8*)(base + (size_t)s3 * 32);
#pragma unroll
        for (int j = 0; j < 8; j++)
            acc[j] += ((float)v0[j] + (float)v1[j]) + ((float)v2[j] + (float)v3[j]);
        e += 4;
    }
    for (; e < e1; e++) {
        int s = csr_src[e];
        bf16x8 v = *(const bf16x8*)(base + (size_t)s * 32);
#pragma unroll
        for (int j = 0; j < 8; j++) acc[j] += (float)v[j];
    }
    float nd = norm[node];
    bf16x8 oc, os;
#pragma unroll
    for (int j = 0; j < 8; j++) {
        float c = acc[j] * nd;
        oc[j] = (bf16_t)c;
        os[j] = (bf16_t)(c * nd);
    }
    size_t t = (size_t)tile * TSLICE + (size_t)node * 32 + l * 8;
    *(bf16x8*)(out_c + t) = oc;
    if (SCALED) *(bf16x8*)(out_s + t) = os;
}

// ---------------- MFMA concat-GEMM (tile-major A): out = relu([f0|f1|f2]@W + b) -----
template <int NT, bool LAYER1>
__global__ __launch_bounds__(256) void gemm_mfma(const bf16_t* __restrict__ f0,
                                                 const bf16_t* __restrict__ f1,
                                                 const bf16_t* __restrict__ f2,
                                                 const bf16_t* __restrict__ Wp,
                                                 const float* __restrict__ bias,
                                                 const float* __restrict__ norm,
                                                 bf16_t* __restrict__ out_b,
                                                 bf16_t* __restrict__ out_s,
                                                 float* __restrict__ out_f, int M) {
    int wave = threadIdx.x >> 6;
    int lane = threadIdx.x & 63;
    int q = lane >> 4, ln = lane & 15;
    int row0 = blockIdx.x * 128 + wave * 32;

    f32x4 acc[2][NT] = {};
    const bf16_t* feats[3] = {f0, f1, f2};
    const bf16x8* Wf = (const bf16x8*)Wp;

#pragma unroll
    for (int kc = 0; kc < 12; kc++) {
        // tile-major A: feature (kc>>2), col-tile (kc&3), cols q*8..q*8+7, row stride 32
        const bf16_t* A = feats[kc >> 2] + (size_t)(kc & 3) * TSLICE + q * 8;
        bf16x8 a0 = *(const bf16x8*)(A + (size_t)(row0 + ln) * 32);
        bf16x8 a1 = *(const bf16x8*)(A + (size_t)(row0 + 16 + ln) * 32);
        const bf16x8* Bp = Wf + (size_t)kc * NT * 64 + lane;
#pragma unroll
        for (int nt = 0; nt < NT; nt++) {
            bf16x8 b = Bp[nt * 64];
            acc[0][nt] = __builtin_amdgcn_mfma_f32_16x16x32_bf16(a0, b, acc[0][nt], 0, 0, 0);
            acc[1][nt] = __builtin_amdgcn_mfma_f32_16x16x32_bf16(a1, b, acc[1][nt], 0, 0, 0);
        }
    }

    float bv[NT];
#pragma unroll
    for (int nt = 0; nt < NT; nt++) bv[nt] = bias[nt * 16 + ln];

#pragma unroll
    for (int mt = 0; mt < 2; mt++) {
#pragma unroll
        for (int r = 0; r < 4; r++) {
            int row = row0 + mt * 16 + q * 4 + r;
            if (row >= M) continue;
            float nd = LAYER1 ? norm[row] : 0.f;
#pragma unroll
            for (int nt = 0; nt < NT; nt++) {
                float val = fmaxf(acc[mt][nt][r] + bv[nt], 0.f);
                if (LAYER1) {
                    // tile-major: col = nt*16+ln -> tile nt>>1, in-tile (nt&1)*16+ln
                    size_t t = (size_t)(nt >> 1) * TSLICE + (size_t)row * 32 + (nt & 1) * 16 + ln;
                    out_b[t] = (bf16_t)val;
                    out_s[t] = (bf16_t)(val * nd);
                } else {
                    out_f[(size_t)row * 64 + nt * 16 + ln] = val;
                }
            }
        }
    }
}

// ---------------- parallel per-graph max pool ----------------
__global__ __launch_bounds__(256) void maxpool2(const float* __restrict__ hF,
                                                const int* __restrict__ gid,
                                                unsigned int* __restrict__ out, int n) {
    int wave = threadIdx.x >> 6;
    int lane = threadIdx.x & 63;
    int n0 = blockIdx.x * 256 + wave * 64;
    if (n0 >= n) return;
    int n1 = min(n0 + 64, n);
    int cur = gid[n0];
    float m = 0.f;
    int i = n0;
    for (; i + 4 <= n1; i += 4) {
        int g0 = gid[i + 0], g1 = gid[i + 1], g2 = gid[i + 2], g3 = gid[i + 3];
        float v0 = hF[(size_t)(i + 0) * 64 + lane];
        float v1 = hF[(size_t)(i + 1) * 64 + lane];
        float v2 = hF[(size_t)(i + 2) * 64 + lane];
        float v3 = hF[(size_t)(i + 3) * 64 + lane];
        if (g0 != cur) { atomicMax(&out[cur * 64 + lane], __float_as_uint(m)); cur = g0; m = v0; } else m = fmaxf(m, v0);
        if (g1 != cur) { atomicMax(&out[cur * 64 + lane], __float_as_uint(m)); cur = g1; m = v1; } else m = fmaxf(m, v1);
        if (g2 != cur) { atomicMax(&out[cur * 64 + lane], __float_as_uint(m)); cur = g2; m = v2; } else m = fmaxf(m, v2);
        if (g3 != cur) { atomicMax(&out[cur * 64 + lane], __float_as_uint(m)); cur = g3; m = v3; } else m = fmaxf(m, v3);
    }
    for (; i < n1; i++) {
        int g = gid[i];
        float v = hF[(size_t)i * 64 + lane];
        if (g != cur) { atomicMax(&out[cur * 64 + lane], __float_as_uint(m)); cur = g; m = v; }
        else m = fmaxf(m, v);
    }
    atomicMax(&out[cur * 64 + lane], __float_as_uint(m));
}

extern "C" void kernel_launch(void* const* d_in, const int* in_sizes, int n_in,
                              void* d_out, int out_size, void* d_ws, size_t ws_size,
                              hipStream_t stream) {
    const float* x  = (const float*)d_in[0];
    const float* W1 = (const float*)d_in[1];
    const float* b1 = (const float*)d_in[2];
    const float* W2 = (const float*)d_in[3];
    const float* b2 = (const float*)d_in[4];
    const int* src  = (const int*)d_in[5];
    const int* dst  = (const int*)d_in[6];
    const int* gid  = (const int*)d_in[7];
    float* out = (float*)d_out;

    char* ws = (char*)d_ws;
    size_t off = 0;
    auto take = [&](size_t bytes) {
        void* p = ws + off;
        off = (off + bytes + 255) & ~(size_t)255;
        return p;
    };
    int* deg     = (int*)take((size_t)N_NODES * 4);
    size_t zero_bytes = off;
    float* norm  = (float*)take((size_t)N_NODES * 4);
    int* row_off = (int*)take((size_t)(N_NODES + 1) * 4);
    int* partial = (int*)take(64 * 4);
    int* rank    = (int*)take((size_t)N_EDGES * 4);
    int* csr_src = (int*)take((size_t)N_EDGES * 4);
    bf16_t* Wp1  = (bf16_t*)take((size_t)384 * 128 * 2);
    bf16_t* Wp2  = (bf16_t*)take((size_t)384 * 64 * 2);
    bf16_t* B0 = (bf16_t*)take((size_t)M_PAD * 128 * 2);  // xb   -> hF (fp32 64c)
    bf16_t* B1 = (bf16_t*)take((size_t)M_PAD * 128 * 2);  // xs   -> hL1s
    bf16_t* B2 = (bf16_t*)take((size_t)M_PAD * 128 * 2);  // c1   -> d1
    bf16_t* B3 = (bf16_t*)take((size_t)M_PAD * 128 * 2);  // c2   -> d2
    bf16_t* B4 = (bf16_t*)take((size_t)M_PAD * 128 * 2);  // c1s  -> d1s
    bf16_t* B5 = (bf16_t*)take((size_t)M_PAD * 128 * 2);  // hL1
    (void)ws_size; (void)in_sizes; (void)n_in; (void)out_size;

    hipMemsetAsync(d_ws, 0, zero_bytes, stream);
    hipMemsetAsync(d_out, 0, (size_t)N_GRAPHS * 64 * 4, stream);

    degk<<<(N_EDGES + 255) / 256, 256, 0, stream>>>(dst, deg, rank, N_EDGES);
    int nchunks = (N_NODES + 1023) / 1024;
    scan1<<<nchunks, 1024, 0, stream>>>(deg, row_off, partial, norm, N_NODES);
    scan3<<<(N_NODES + 255) / 256, 256, 0, stream>>>(row_off, partial, N_NODES);
    midk<<<NPRE + NSC + NPW, 256, 0, stream>>>(x, norm, B0, B1, src, dst, row_off, rank,
                                               csr_src, W1, Wp1, W2, Wp2);

    int spmm_grid = 8 * 391;              // 3128: xcd-spatial, 64 nodes/block, 4 tiles
    int gemm_grid = M_PAD / 128;          // 392

    // layer 1 hops
    spmm_xcd<true><<<spmm_grid, 256, 0, stream>>>(B1, B2, B4, norm, row_off, csr_src, N_NODES);
    spmm_xcd<false><<<spmm_grid, 256, 0, stream>>>(B4, B3, nullptr, norm, row_off, csr_src, N_NODES);
    // layer 1 GEMM -> hL1 (B5) + hL1s (B1), tile-major
    gemm_mfma<8, true><<<gemm_grid, 256, 0, stream>>>(B0, B2, B3, Wp1, b1, norm, B5, B1, nullptr, N_NODES);
    // layer 2 hops
    spmm_xcd<true><<<spmm_grid, 256, 0, stream>>>(B1, B2, B4, norm, row_off, csr_src, N_NODES);
    spmm_xcd<false><<<spmm_grid, 256, 0, stream>>>(B4, B3, nullptr, norm, row_off, csr_src, N_NODES);
    // layer 2 GEMM -> hF (B0 as fp32, 64 cols, node-major)
    gemm_mfma<4, false><<<gemm_grid, 256, 0, stream>>>(B5, B2, B3, Wp2, b2, nullptr, nullptr, nullptr, (float*)B0, N_NODES);
    // readout
    maxpool2<<<(N_NODES + 255) / 256, 256, 0, stream>>>((const float*)B0, gid, (unsigned int*)out, N_NODES);
}